// Round 1
// baseline (1016.362 us; speedup 1.0000x reference)
//
#include <hip/hip_runtime.h>
#include <math.h>

#define NCH 8
#define HID 20

// ---- workspace layout (float offsets) ----
#define OFF_F    0u            // 13*576*81   = 606528
#define OFF_BAB  606528u       // 13*576*9    = 67392
#define OFF_E    673920u       // 13*9*576*28 = 1886976  (row: E[0..24], [25]=beta)
#define OFF_I1   2560896u      // 8*64*64
#define OFF_I2   2593664u      // 8*32*32
#define OFF_XA   2601856u      // 8*8*128*128
#define OFF_XB   3650432u
#define OFF_X1A  4699008u      // 8*8*64*64
#define OFF_X1B  4961152u
#define OFF_X2A  5223296u      // 8*8*32*32
#define OFF_X2B  5288832u
// total 5354368 floats = ~20.4 MB

// F[blk][p][ab][a'b'] = sum_c W2[p,c,ab] * W1[g*HID+c, a'b'] ; Bab[blk][p][ab] = sum_c W2[p,c,ab]*b1[g*HID+c]
__global__ __launch_bounds__(256) void precomp_f(
    const float* __restrict__ iW1, const float* __restrict__ iW2, const float* __restrict__ ib1,
    const float* __restrict__ bW1, const float* __restrict__ bW2, const float* __restrict__ bb1,
    float* __restrict__ F, float* __restrict__ Bab)
{
  int tid = blockIdx.x * 256 + threadIdx.x;
  if (tid >= 13 * 576 * 81) return;
  int ab9 = tid % 81;
  int rest = tid / 81;
  int p = rest % 576;
  int blk = rest / 576;
  if (blk == 0 && p >= 72) return;
  int ab = ab9 / 9, apbp = ab9 % 9;
  const float *W2, *W1, *b1;
  if (blk == 0) { W2 = iW2; W1 = iW1; b1 = ib1; }
  else {
    W2 = bW2 + (size_t)(blk - 1) * 576 * HID * 9;
    W1 = bW1 + (size_t)(blk - 1) * 64 * HID * 9;
    b1 = bb1 + (size_t)(blk - 1) * 64 * HID;
  }
  int g = p / 9;
  const float* w2p = W2 + (size_t)p * HID * 9 + ab;
  const float* w1p = W1 + (size_t)g * HID * 9 + apbp;
  float s = 0.f;
  #pragma unroll
  for (int cc = 0; cc < HID; ++cc) s = fmaf(w2p[cc * 9], w1p[cc * 9], s);
  F[(size_t)(blk * 576 + p) * 81 + ab9] = s;
  if (apbp == 0) {
    const float* b1p = b1 + g * HID;
    float sb = 0.f;
    #pragma unroll
    for (int cc = 0; cc < HID; ++cc) sb = fmaf(w2p[cc * 9], b1p[cc], sb);
    Bab[(size_t)(blk * 576 + p) * 9 + ab] = sb;
  }
}

// E-class tables: cls = yclass*3+xclass; yclass 0=top(y==0),1=free,2=bot; restricts valid W2 taps.
__global__ __launch_bounds__(256) void precomp_e(
    const float* __restrict__ F, const float* __restrict__ Bab,
    const float* __restrict__ ib2, const float* __restrict__ bb2,
    float* __restrict__ E)
{
  int tid = blockIdx.x * 256 + threadIdx.x;
  if (tid >= 13 * 9 * 576 * 25) return;
  int uv = tid % 25;
  int rest = tid / 25;
  int p = rest % 576;
  int rest2 = rest / 576;
  int cls = rest2 % 9;
  int blk = rest2 / 9;
  if (blk == 0 && p >= 72) return;
  int yc = cls / 3, xc = cls % 3;
  int alo = (yc == 0) ? 1 : 0, ahi = (yc == 2) ? 1 : 2;
  int blo = (xc == 0) ? 1 : 0, bhi = (xc == 2) ? 1 : 2;
  int u = uv / 5, v = uv % 5;
  const float* Fp = F + (size_t)(blk * 576 + p) * 81;
  float s = 0.f;
  for (int a = alo; a <= ahi; ++a) {
    int a2 = u - a;
    if (a2 < 0 || a2 > 2) continue;
    for (int bq = blo; bq <= bhi; ++bq) {
      int b2i = v - bq;
      if (b2i < 0 || b2i > 2) continue;
      s += Fp[(a * 3 + bq) * 9 + a2 * 3 + b2i];
    }
  }
  float* Ep = E + (size_t)((blk * 9 + cls) * 576 + p) * 28;
  Ep[uv] = s;
  if (uv == 0) {
    float beta = (blk == 0) ? ib2[p] : bb2[(size_t)(blk - 1) * 576 + p];
    const float* Bp = Bab + (size_t)(blk * 576 + p) * 9;
    for (int a = alo; a <= ahi; ++a)
      for (int bq = blo; bq <= bhi; ++bq)
        beta += Bp[a * 3 + bq];
    Ep[25] = beta;
  }
}

__global__ __launch_bounds__(256) void img_down(
    const float* __restrict__ image, float* __restrict__ i1, float* __restrict__ i2)
{
  int tid = blockIdx.x * 256 + threadIdx.x;
  if (tid < 8 * 64 * 64) {
    int xx = tid % 64, y = (tid / 64) % 64, b = tid / 4096;
    const float* p = image + ((size_t)b * 128 + y * 2) * 128 + xx * 2;
    i1[tid] = 0.25f * (p[0] + p[1] + p[128] + p[129]);
  } else {
    int t = tid - 8 * 64 * 64;
    if (t >= 8 * 32 * 32) return;
    int xx = t % 32, y = (t / 32) % 32, b = t / 1024;
    const float* p = image + ((size_t)b * 128 + y * 4) * 128 + xx * 4;
    float s = 0.f;
    #pragma unroll
    for (int rr = 0; rr < 4; ++rr)
      #pragma unroll
      for (int cc = 0; cc < 4; ++cc) s += p[rr * 128 + cc];
    i2[t] = s * 0.0625f;
  }
}

__global__ __launch_bounds__(256) void x_down(
    const float* __restrict__ x, float* __restrict__ x1, float* __restrict__ x2)
{
  int tid = blockIdx.x * 256 + threadIdx.x;
  if (tid < 8 * NCH * 64 * 64) {
    int xx = tid % 64, y = (tid / 64) % 64, rest = tid / 4096; // rest = b*8+ch
    const float* p = x + ((size_t)rest * 128 + y * 2) * 128 + xx * 2;
    x1[tid] = 0.25f * (p[0] + p[1] + p[128] + p[129]);
  } else {
    int t = tid - 8 * NCH * 64 * 64;
    if (t >= 8 * NCH * 32 * 32) return;
    int xx = t % 32, y = (t / 32) % 32, rest = t / 1024;
    const float* p = x + ((size_t)rest * 128 + y * 4) * 128 + xx * 4;
    float s = 0.f;
    #pragma unroll
    for (int rr = 0; rr < 4; ++rr)
      #pragma unroll
      for (int cc = 0; cc < 4; ++cc) s += p[rr * 128 + cc];
    x2[t] = s * 0.0625f;
  }
}

#define TW 32
#define TH 16

// Fused spatially-varying conv: out[o] = elu( sum_{i,k} (beta + E . imgpatch)[o,i,k] * x_i(shift k) )
// Interior-exact; 1-px border fixed up by sm_border afterwards.
__global__ __launch_bounds__(256) void sm_apply(
    const float* __restrict__ xi0, float* __restrict__ xo0, const float* __restrict__ im0, const float* __restrict__ E0, int N0, int nci0,
    const float* __restrict__ xi1, float* __restrict__ xo1, const float* __restrict__ im1, const float* __restrict__ E1, int N1, int nci1,
    const float* __restrict__ xi2, float* __restrict__ xo2, const float* __restrict__ im2, const float* __restrict__ E2, int N2, int nci2,
    int n0, int n01)
{
  const float* __restrict__ xin;
  float* __restrict__ xout;
  const float* __restrict__ img;
  const float* __restrict__ E;
  int N, nci, lb;
  int bid = blockIdx.x;
  if (bid < n0)       { xin = xi0; xout = xo0; img = im0; E = E0; N = N0; nci = nci0; lb = bid; }
  else if (bid < n01) { xin = xi1; xout = xo1; img = im1; E = E1; N = N1; nci = nci1; lb = bid - n0; }
  else                { xin = xi2; xout = xo2; img = im2; E = E2; N = N2; nci = nci2; lb = bid - n01; }

  int tilesx = N / TW, tilesy = N / TH;
  int tiles = tilesx * tilesy;
  int b = lb / tiles;
  int trem = lb % tiles;
  int ty = trem / tilesx, tx = trem % tilesx;
  int X0 = tx * TW, Y0 = ty * TH;

  __shared__ float xs[NCH][TH + 2][TW + 2];   // x tile, halo 1
  __shared__ float is[TH + 4][TW + 4];        // img tile, halo 2

  const float* imgb = img + (size_t)b * N * N;
  for (int idx = threadIdx.x; idx < (TH + 4) * (TW + 4); idx += 256) {
    int rr = idx / (TW + 4), cc = idx % (TW + 4);
    int gy = Y0 + rr - 2, gx = X0 + cc - 2;
    float v = 0.f;
    if (gy >= 0 && gy < N && gx >= 0 && gx < N) v = imgb[gy * N + gx];
    is[rr][cc] = v;
  }
  const float* xinb = xin + (size_t)b * nci * N * N;
  for (int idx = threadIdx.x; idx < nci * (TH + 2) * (TW + 2); idx += 256) {
    int cc = idx % (TW + 2);
    int rr = idx / (TW + 2);
    int r2 = rr % (TH + 2);
    int i = rr / (TH + 2);
    int gy = Y0 + r2 - 1, gx = X0 + cc - 1;
    float v = 0.f;
    if (gy >= 0 && gy < N && gx >= 0 && gx < N) v = xinb[(size_t)i * N * N + gy * N + gx];
    xs[i][r2][cc] = v;
  }
  __syncthreads();

  int c = threadIdx.x % TW;  // 0..31
  int r = threadIdx.x / TW;  // 0..7 -> handles rows r and r+8

  float P0[25], P1[25];
  #pragma unroll
  for (int u = 0; u < 5; ++u)
    #pragma unroll
    for (int v = 0; v < 5; ++v) {
      P0[u * 5 + v] = is[r + u][c + v];
      P1[u * 5 + v] = is[r + 8 + u][c + v];
    }

  float acc[NCH][2];
  #pragma unroll
  for (int o = 0; o < NCH; ++o) { acc[o][0] = 0.f; acc[o][1] = 0.f; }

  const int nik = nci * 9;
  for (int i = 0; i < nci; ++i) {
    #pragma unroll 1
    for (int k9 = 0; k9 < 9; ++k9) {
      const int dy = k9 / 3, dx = k9 % 3;
      const float xp0 = xs[i][r + dy][c + dx];
      const float xp1 = xs[i][r + 8 + dy][c + dx];
      const float* __restrict__ e0 = E + (size_t)(i * 9 + k9) * 28;
      #pragma unroll
      for (int o = 0; o < NCH; ++o) {
        const float* __restrict__ e = e0 + (size_t)o * nik * 28;
        float kv0 = e[25], kv1 = e[25];
        #pragma unroll
        for (int uv = 0; uv < 25; ++uv) {
          kv0 = fmaf(e[uv], P0[uv], kv0);
          kv1 = fmaf(e[uv], P1[uv], kv1);
        }
        acc[o][0] = fmaf(kv0, xp0, acc[o][0]);
        acc[o][1] = fmaf(kv1, xp1, acc[o][1]);
      }
    }
  }

  const int gx = X0 + c, gy0 = Y0 + r, gy1 = Y0 + r + 8;
  float* yb = xout + (size_t)b * NCH * N * N;
  #pragma unroll
  for (int o = 0; o < NCH; ++o) {
    float v0 = acc[o][0]; v0 = v0 > 0.f ? v0 : expm1f(v0);
    float v1 = acc[o][1]; v1 = v1 > 0.f ? v1 : expm1f(v1);
    yb[(size_t)o * N * N + gy0 * N + gx] = v0;
    yb[(size_t)o * N * N + gy1 * N + gx] = v1;
  }
}

// Exact recompute of the 1-px output border using class-selected E tables.
__global__ __launch_bounds__(256) void sm_border(
    const float* __restrict__ xi0, float* __restrict__ xo0, const float* __restrict__ im0, const float* __restrict__ E0, int N0, int nci0,
    const float* __restrict__ xi1, float* __restrict__ xo1, const float* __restrict__ im1, const float* __restrict__ E1, int N1, int nci1,
    const float* __restrict__ xi2, float* __restrict__ xo2, const float* __restrict__ im2, const float* __restrict__ E2, int N2, int nci2,
    int t0, int t01, int t012)
{
  int tid = blockIdx.x * 256 + threadIdx.x;
  if (tid >= t012) return;
  const float* __restrict__ xin;
  float* __restrict__ xout;
  const float* __restrict__ img;
  const float* __restrict__ E;
  int N, nci, lt;
  if (tid < t0)       { xin = xi0; xout = xo0; img = im0; E = E0; N = N0; nci = nci0; lt = tid; }
  else if (tid < t01) { xin = xi1; xout = xo1; img = im1; E = E1; N = N1; nci = nci1; lt = tid - t0; }
  else                { xin = xi2; xout = xo2; img = im2; E = E2; N = N2; nci = nci2; lt = tid - t01; }

  int per = 4 * N - 4;
  int bp = lt % per;
  int rest = lt / per;
  int o = rest % NCH;
  int b = rest / NCH;
  int y, x;
  if (bp < N)            { y = 0;                   x = bp; }
  else if (bp < 2 * N)   { y = N - 1;               x = bp - N; }
  else if (bp < 3 * N - 2) { x = 0;                 y = 1 + (bp - 2 * N); }
  else                   { x = N - 1;               y = 1 + (bp - (3 * N - 2)); }
  int yc = (y == 0) ? 0 : ((y == N - 1) ? 2 : 1);
  int xc = (x == 0) ? 0 : ((x == N - 1) ? 2 : 1);
  const float* __restrict__ Eb = E + (size_t)(yc * 3 + xc) * 576 * 28;

  const float* imb = img + (size_t)b * N * N;
  float P[25];
  #pragma unroll
  for (int u = 0; u < 5; ++u)
    #pragma unroll
    for (int v = 0; v < 5; ++v) {
      int gy = y + u - 2, gx = x + v - 2;
      P[u * 5 + v] = (gy >= 0 && gy < N && gx >= 0 && gx < N) ? imb[gy * N + gx] : 0.f;
    }

  const float* xb = xin + (size_t)b * nci * N * N;
  const int nik = nci * 9;
  float out = 0.f;
  for (int i = 0; i < nci; ++i) {
    #pragma unroll 1
    for (int k9 = 0; k9 < 9; ++k9) {
      int yy = y + k9 / 3 - 1, xx = x + k9 % 3 - 1;
      float xv = (yy >= 0 && yy < N && xx >= 0 && xx < N) ? xb[(size_t)i * N * N + yy * N + xx] : 0.f;
      const float* __restrict__ e = Eb + (size_t)((o * nci + i) * 9 + k9) * 28;
      float kv = e[25];
      #pragma unroll
      for (int uv = 0; uv < 25; ++uv) kv = fmaf(e[uv], P[uv], kv);
      out = fmaf(kv, xv, out);
    }
  }
  out = out > 0.f ? out : expm1f(out);
  xout[((size_t)b * NCH + o) * N * N + y * N + x] = out;
}

__global__ __launch_bounds__(256) void final_merge(
    const float* __restrict__ x, const float* __restrict__ x1, const float* __restrict__ x2,
    const float* __restrict__ w5, const float* __restrict__ b5,
    const float* __restrict__ w6, const float* __restrict__ b6,
    float* __restrict__ out)
{
  int tid = blockIdx.x * 256 + threadIdx.x;
  if (tid >= 8 * 128 * 128) return;
  int xx = tid % 128, y = (tid / 128) % 128, b = tid / 16384;
  float v[NCH];
  #pragma unroll
  for (int i = 0; i < NCH; ++i) {
    v[i] = x[((size_t)(b * NCH + i) * 128 + y) * 128 + xx]
         + x1[((size_t)(b * NCH + i) * 64 + (y >> 1)) * 64 + (xx >> 1)]
         + x2[((size_t)(b * NCH + i) * 32 + (y >> 2)) * 32 + (xx >> 2)];
  }
  float o6 = b6[0];
  #pragma unroll
  for (int o = 0; o < NCH; ++o) {
    float h = b5[o];
    #pragma unroll
    for (int i = 0; i < NCH; ++i) h = fmaf(w5[o * NCH + i], v[i], h);
    h = h > 0.f ? h : expm1f(h);
    o6 = fmaf(w6[o], h, o6);
  }
  out[tid] = o6;
}

extern "C" void kernel_launch(void* const* d_in, const int* in_sizes, int n_in,
                              void* d_out, int out_size, void* d_ws, size_t ws_size,
                              hipStream_t stream) {
  const float* image = (const float*)d_in[0];
  const float* x_in  = (const float*)d_in[1];
  const float* iW1   = (const float*)d_in[2];
  const float* ib1   = (const float*)d_in[3];
  const float* iW2   = (const float*)d_in[4];
  const float* ib2   = (const float*)d_in[5];
  const float* bW1   = (const float*)d_in[6];
  const float* bb1   = (const float*)d_in[7];
  const float* bW2   = (const float*)d_in[8];
  const float* bb2   = (const float*)d_in[9];
  const float* w5    = (const float*)d_in[10];
  const float* b5    = (const float*)d_in[11];
  const float* w6    = (const float*)d_in[12];
  const float* b6    = (const float*)d_in[13];
  float* ws = (float*)d_ws;

  float* F   = ws + OFF_F;
  float* Bab = ws + OFF_BAB;
  float* E   = ws + OFF_E;
  float* i1  = ws + OFF_I1;
  float* i2  = ws + OFF_I2;
  float* xA  = ws + OFF_XA;
  float* xB  = ws + OFF_XB;
  float* x1A = ws + OFF_X1A;
  float* x1B = ws + OFF_X1B;
  float* x2A = ws + OFF_X2A;
  float* x2B = ws + OFF_X2B;

  precomp_f<<<2370, 256, 0, stream>>>(iW1, iW2, ib1, bW1, bW2, bb1, F, Bab);
  precomp_e<<<6582, 256, 0, stream>>>(F, Bab, ib2, bb2, E);
  img_down<<<160, 256, 0, stream>>>(image, i1, i2);

  // ---- init block (blk 0, nc_in = 1, N = 128) ----
  const size_t EBLK = (size_t)9 * 576 * 28;
  const float* Em = E + 0 * EBLK + 4 * (size_t)576 * 28;  // interior class
  sm_apply<<<256, 256, 0, stream>>>(
      x_in, xA, image, Em, 128, 1,
      x_in, xA, image, Em, 128, 1,
      x_in, xA, image, Em, 128, 1,
      256, 256);
  sm_border<<<127, 256, 0, stream>>>(
      x_in, xA, image, E + 0 * EBLK, 128, 1,
      x_in, xA, image, E + 0 * EBLK, 128, 1,
      x_in, xA, image, E + 0 * EBLK, 128, 1,
      32512, 32512, 32512);
  x_down<<<1280, 256, 0, stream>>>(xA, x1A, x2A);

  float* xr = xA; float* xw = xB;
  float* x1r = x1A; float* x1w = x1B;
  float* x2r = x2A; float* x2w = x2B;
  for (int t = 0; t < 4; ++t) {
    int blk0 = 1 + 3 * t, blk1 = 2 + 3 * t, blk2 = 3 + 3 * t;
    const float* Em0 = E + blk0 * EBLK + 4 * (size_t)576 * 28;
    const float* Em1 = E + blk1 * EBLK + 4 * (size_t)576 * 28;
    const float* Em2 = E + blk2 * EBLK + 4 * (size_t)576 * 28;
    sm_apply<<<336, 256, 0, stream>>>(
        xr, xw, image, Em0, 128, 8,
        x1r, x1w, i1, Em1, 64, 8,
        x2r, x2w, i2, Em2, 32, 8,
        256, 320);
    sm_border<<<221, 256, 0, stream>>>(
        xr, xw, image, E + blk0 * EBLK, 128, 8,
        x1r, x1w, i1, E + blk1 * EBLK, 64, 8,
        x2r, x2w, i2, E + blk2 * EBLK, 32, 8,
        32512, 32512 + 16128, 32512 + 16128 + 7936);
    // swap ping-pong
    float* tmp;
    tmp = xr; xr = xw; xw = tmp;
    tmp = x1r; x1r = x1w; x1w = tmp;
    tmp = x2r; x2r = x2w; x2w = tmp;
  }
  // after 4 steps the latest tensors are in xr/x1r/x2r (== A buffers)
  final_merge<<<512, 256, 0, stream>>>(xr, x1r, x2r, w5, b5, w6, b6, (float*)d_out);
}

// Round 2
// 814.442 us; speedup vs baseline: 1.2479x; 1.2479x over previous
//
#include <hip/hip_runtime.h>
#include <math.h>

#define NCH 8
#define HID 20

// ---- workspace layout (float offsets) ----
#define OFF_F    0u            // 13*576*81   = 606528
#define OFF_BAB  606528u       // 13*576*9    = 67392
#define OFF_E    673920u       // 13*9*576*28 = 1886976  (row: E[0..24], [25]=beta)
#define OFF_I1   2560896u      // 8*64*64
#define OFF_I2   2593664u      // 8*32*32
#define OFF_XA   2601856u      // 8*8*128*128
#define OFF_XB   3650432u
#define OFF_X1A  4699008u      // 8*8*64*64
#define OFF_X1B  4961152u
#define OFF_X2A  5223296u      // 8*8*32*32
#define OFF_X2B  5288832u

// F[blk][p][ab][a'b'] = sum_c W2[p,c,ab] * W1[g*HID+c, a'b'] ; Bab = sum_c W2[p,c,ab]*b1[g*HID+c]
__global__ __launch_bounds__(256) void precomp_f(
    const float* __restrict__ iW1, const float* __restrict__ iW2, const float* __restrict__ ib1,
    const float* __restrict__ bW1, const float* __restrict__ bW2, const float* __restrict__ bb1,
    float* __restrict__ F, float* __restrict__ Bab)
{
  int tid = blockIdx.x * 256 + threadIdx.x;
  if (tid >= 13 * 576 * 81) return;
  int ab9 = tid % 81;
  int rest = tid / 81;
  int p = rest % 576;
  int blk = rest / 576;
  if (blk == 0 && p >= 72) return;
  int ab = ab9 / 9, apbp = ab9 % 9;
  const float *W2, *W1, *b1;
  if (blk == 0) { W2 = iW2; W1 = iW1; b1 = ib1; }
  else {
    W2 = bW2 + (size_t)(blk - 1) * 576 * HID * 9;
    W1 = bW1 + (size_t)(blk - 1) * 64 * HID * 9;
    b1 = bb1 + (size_t)(blk - 1) * 64 * HID;
  }
  int g = p / 9;
  const float* w2p = W2 + (size_t)p * HID * 9 + ab;
  const float* w1p = W1 + (size_t)g * HID * 9 + apbp;
  float s = 0.f;
  #pragma unroll
  for (int cc = 0; cc < HID; ++cc) s = fmaf(w2p[cc * 9], w1p[cc * 9], s);
  F[(size_t)(blk * 576 + p) * 81 + ab9] = s;
  if (apbp == 0) {
    const float* b1p = b1 + g * HID;
    float sb = 0.f;
    #pragma unroll
    for (int cc = 0; cc < HID; ++cc) sb = fmaf(w2p[cc * 9], b1p[cc], sb);
    Bab[(size_t)(blk * 576 + p) * 9 + ab] = sb;
  }
}

// E-class tables: cls = yclass*3+xclass; yclass 0=top(y==0),1=free,2=bot; restricts valid W2 taps.
__global__ __launch_bounds__(256) void precomp_e(
    const float* __restrict__ F, const float* __restrict__ Bab,
    const float* __restrict__ ib2, const float* __restrict__ bb2,
    float* __restrict__ E)
{
  int tid = blockIdx.x * 256 + threadIdx.x;
  if (tid >= 13 * 9 * 576 * 25) return;
  int uv = tid % 25;
  int rest = tid / 25;
  int p = rest % 576;
  int rest2 = rest / 576;
  int cls = rest2 % 9;
  int blk = rest2 / 9;
  if (blk == 0 && p >= 72) return;
  int yc = cls / 3, xc = cls % 3;
  int alo = (yc == 0) ? 1 : 0, ahi = (yc == 2) ? 1 : 2;
  int blo = (xc == 0) ? 1 : 0, bhi = (xc == 2) ? 1 : 2;
  int u = uv / 5, v = uv % 5;
  const float* Fp = F + (size_t)(blk * 576 + p) * 81;
  float s = 0.f;
  for (int a = alo; a <= ahi; ++a) {
    int a2 = u - a;
    if (a2 < 0 || a2 > 2) continue;
    for (int bq = blo; bq <= bhi; ++bq) {
      int b2i = v - bq;
      if (b2i < 0 || b2i > 2) continue;
      s += Fp[(a * 3 + bq) * 9 + a2 * 3 + b2i];
    }
  }
  float* Ep = E + (size_t)((blk * 9 + cls) * 576 + p) * 28;
  Ep[uv] = s;
  if (uv == 0) {
    float beta = (blk == 0) ? ib2[p] : bb2[(size_t)(blk - 1) * 576 + p];
    const float* Bp = Bab + (size_t)(blk * 576 + p) * 9;
    for (int a = alo; a <= ahi; ++a)
      for (int bq = blo; bq <= bhi; ++bq)
        beta += Bp[a * 3 + bq];
    Ep[25] = beta;
  }
}

__global__ __launch_bounds__(256) void img_down(
    const float* __restrict__ image, float* __restrict__ i1, float* __restrict__ i2)
{
  int tid = blockIdx.x * 256 + threadIdx.x;
  if (tid < 8 * 64 * 64) {
    int xx = tid % 64, y = (tid / 64) % 64, b = tid / 4096;
    const float* p = image + ((size_t)b * 128 + y * 2) * 128 + xx * 2;
    i1[tid] = 0.25f * (p[0] + p[1] + p[128] + p[129]);
  } else {
    int t = tid - 8 * 64 * 64;
    if (t >= 8 * 32 * 32) return;
    int xx = t % 32, y = (t / 32) % 32, b = t / 1024;
    const float* p = image + ((size_t)b * 128 + y * 4) * 128 + xx * 4;
    float s = 0.f;
    #pragma unroll
    for (int rr = 0; rr < 4; ++rr)
      #pragma unroll
      for (int cc = 0; cc < 4; ++cc) s += p[rr * 128 + cc];
    i2[t] = s * 0.0625f;
  }
}

__global__ __launch_bounds__(256) void x_down(
    const float* __restrict__ x, float* __restrict__ x1, float* __restrict__ x2)
{
  int tid = blockIdx.x * 256 + threadIdx.x;
  if (tid < 8 * NCH * 64 * 64) {
    int xx = tid % 64, y = (tid / 64) % 64, rest = tid / 4096;
    const float* p = x + ((size_t)rest * 128 + y * 2) * 128 + xx * 2;
    x1[tid] = 0.25f * (p[0] + p[1] + p[128] + p[129]);
  } else {
    int t = tid - 8 * NCH * 64 * 64;
    if (t >= 8 * NCH * 32 * 32) return;
    int xx = t % 32, y = (t / 32) % 32, rest = t / 1024;
    const float* p = x + ((size_t)rest * 128 + y * 4) * 128 + xx * 4;
    float s = 0.f;
    #pragma unroll
    for (int rr = 0; rr < 4; ++rr)
      #pragma unroll
      for (int cc = 0; cc < 4; ++cc) s += p[rr * 128 + cc];
    x2[t] = s * 0.0625f;
  }
}

#define TW 32
#define TH 16
#define NOG 4   // o-groups per tile
#define OG 2    // output channels per group

// Fused spatially-varying conv, interior-exact (borders fixed by sm_edge/sm_corner).
// Block handles one (b, tile, og): OG=2 output channels, 2 px/thread.
__global__ __launch_bounds__(256, 4) void sm_apply(
    const float* __restrict__ xi0, float* __restrict__ xo0, const float* __restrict__ im0, const float* __restrict__ E0, int N0, int nci0,
    const float* __restrict__ xi1, float* __restrict__ xo1, const float* __restrict__ im1, const float* __restrict__ E1, int N1, int nci1,
    const float* __restrict__ xi2, float* __restrict__ xo2, const float* __restrict__ im2, const float* __restrict__ E2, int N2, int nci2,
    int n0, int n01)
{
  const float* __restrict__ xin;
  float* __restrict__ xout;
  const float* __restrict__ img;
  const float* __restrict__ E;
  int N, nci, lb;
  int bid = blockIdx.x;
  if (bid < n0)       { xin = xi0; xout = xo0; img = im0; E = E0; N = N0; nci = nci0; lb = bid; }
  else if (bid < n01) { xin = xi1; xout = xo1; img = im1; E = E1; N = N1; nci = nci1; lb = bid - n0; }
  else                { xin = xi2; xout = xo2; img = im2; E = E2; N = N2; nci = nci2; lb = bid - n01; }

  int og = lb & (NOG - 1);
  int rem = lb >> 2;
  int tilesx = N / TW, tilesy = N / TH;
  int tiles = tilesx * tilesy;
  int b = rem / tiles;
  int trem = rem % tiles;
  int ty = trem / tilesx, tx = trem % tilesx;
  int X0 = tx * TW, Y0 = ty * TH;

  __shared__ float xs[NCH][TH + 2][TW + 2];   // x tile, halo 1
  __shared__ float is[TH + 4][TW + 4];        // img tile, halo 2

  const float* imgb = img + (size_t)b * N * N;
  for (int idx = threadIdx.x; idx < (TH + 4) * (TW + 4); idx += 256) {
    int rr = idx / (TW + 4), cc = idx % (TW + 4);
    int gy = Y0 + rr - 2, gx = X0 + cc - 2;
    float v = 0.f;
    if (gy >= 0 && gy < N && gx >= 0 && gx < N) v = imgb[gy * N + gx];
    is[rr][cc] = v;
  }
  const float* xinb = xin + (size_t)b * nci * N * N;
  for (int idx = threadIdx.x; idx < nci * (TH + 2) * (TW + 2); idx += 256) {
    int cc = idx % (TW + 2);
    int rr = idx / (TW + 2);
    int r2 = rr % (TH + 2);
    int i = rr / (TH + 2);
    int gy = Y0 + r2 - 1, gx = X0 + cc - 1;
    float v = 0.f;
    if (gy >= 0 && gy < N && gx >= 0 && gx < N) v = xinb[(size_t)i * N * N + gy * N + gx];
    xs[i][r2][cc] = v;
  }
  __syncthreads();

  int c = threadIdx.x % TW;  // 0..31
  int r = threadIdx.x / TW;  // 0..7 -> handles rows r and r+8

  float P0[25], P1[25];
  #pragma unroll
  for (int u = 0; u < 5; ++u)
    #pragma unroll
    for (int v = 0; v < 5; ++v) {
      P0[u * 5 + v] = is[r + u][c + v];
      P1[u * 5 + v] = is[r + 8 + u][c + v];
    }

  float a00 = 0.f, a01 = 0.f, a10 = 0.f, a11 = 0.f;  // [o][px]
  const int o0 = og * OG;
  const size_t row28 = 28;
  const float* __restrict__ Ea = E + (size_t)(o0 * nci) * 9 * row28;
  const float* __restrict__ Eb = E + (size_t)((o0 + 1) * nci) * 9 * row28;

  for (int i = 0; i < nci; ++i) {
    #pragma unroll 3
    for (int k9 = 0; k9 < 9; ++k9) {
      const int dy = k9 / 3, dx = k9 % 3;
      const float xp0 = xs[i][r + dy][c + dx];
      const float xp1 = xs[i][r + 8 + dy][c + dx];
      const float* __restrict__ e0 = Ea + (size_t)(i * 9 + k9) * row28;
      const float* __restrict__ e1 = Eb + (size_t)(i * 9 + k9) * row28;
      float k00 = e0[25], k01 = e0[25], k10 = e1[25], k11 = e1[25];
      #pragma unroll
      for (int uv = 0; uv < 25; ++uv) {
        k00 = fmaf(e0[uv], P0[uv], k00);
        k01 = fmaf(e0[uv], P1[uv], k01);
        k10 = fmaf(e1[uv], P0[uv], k10);
        k11 = fmaf(e1[uv], P1[uv], k11);
      }
      a00 = fmaf(k00, xp0, a00);
      a01 = fmaf(k01, xp1, a01);
      a10 = fmaf(k10, xp0, a10);
      a11 = fmaf(k11, xp1, a11);
    }
  }

  const int gx = X0 + c, gy0 = Y0 + r, gy1 = Y0 + r + 8;
  float* yb = xout + (size_t)b * NCH * N * N;
  float v00 = a00 > 0.f ? a00 : expm1f(a00);
  float v01 = a01 > 0.f ? a01 : expm1f(a01);
  float v10 = a10 > 0.f ? a10 : expm1f(a10);
  float v11 = a11 > 0.f ? a11 : expm1f(a11);
  yb[(size_t)o0 * N * N + gy0 * N + gx] = v00;
  yb[(size_t)o0 * N * N + gy1 * N + gx] = v01;
  yb[(size_t)(o0 + 1) * N * N + gy0 * N + gx] = v10;
  yb[(size_t)(o0 + 1) * N * N + gy1 * N + gx] = v11;
}

// Edge pixels (excluding 4 corners): class is block-uniform -> E via scalar loads.
// Blocks per scale: 4 sides * 8 b * H (H = #64-chunks along the edge).
__global__ __launch_bounds__(256) void sm_edge(
    const float* __restrict__ xi0, float* __restrict__ xo0, const float* __restrict__ im0, const float* __restrict__ E0, int N0, int nci0,
    const float* __restrict__ xi1, float* __restrict__ xo1, const float* __restrict__ im1, const float* __restrict__ E1, int N1, int nci1,
    const float* __restrict__ xi2, float* __restrict__ xo2, const float* __restrict__ im2, const float* __restrict__ E2, int N2, int nci2,
    int nb0, int nb01)
{
  const float* __restrict__ xin;
  float* __restrict__ xout;
  const float* __restrict__ img;
  const float* __restrict__ E;
  int N, nci, lb;
  int bid = blockIdx.x;
  if (bid < nb0)       { xin = xi0; xout = xo0; img = im0; E = E0; N = N0; nci = nci0; lb = bid; }
  else if (bid < nb01) { xin = xi1; xout = xo1; img = im1; E = E1; N = N1; nci = nci1; lb = bid - nb0; }
  else                 { xin = xi2; xout = xo2; img = im2; E = E2; N = N2; nci = nci2; lb = bid - nb01; }

  int H = (N - 2 + 63) / 64;
  int half = lb % H;
  int b = (lb / H) % 8;
  int side = lb / (H * 8);

  int lane = threadIdx.x & 63;
  int orow = threadIdx.x >> 6;   // 0..3 (wave-uniform)
  int pos = 1 + half * 64 + lane;
  bool act = pos < N - 1;
  if (!act) pos = 1;

  int y, x, cls;
  if (side == 0)      { y = 0;     x = pos;  cls = 1; }
  else if (side == 1) { y = N - 1; x = pos;  cls = 7; }
  else if (side == 2) { x = 0;     y = pos;  cls = 3; }
  else                { x = N - 1; y = pos;  cls = 5; }

  const float* __restrict__ Eb = E + (size_t)cls * 576 * 28;
  const float* imb = img + (size_t)b * N * N;
  float P[25];
  #pragma unroll
  for (int u = 0; u < 5; ++u)
    #pragma unroll
    for (int v = 0; v < 5; ++v) {
      int gy = y + u - 2, gx = x + v - 2;
      P[u * 5 + v] = (gy >= 0 && gy < N && gx >= 0 && gx < N) ? imb[gy * N + gx] : 0.f;
    }

  const float* xb = xin + (size_t)b * nci * N * N;
  float acc0 = 0.f, acc1 = 0.f;
  const int oA = orow, oB = orow + 4;
  for (int i = 0; i < nci; ++i) {
    #pragma unroll 1
    for (int k9 = 0; k9 < 9; ++k9) {
      int yy = y + k9 / 3 - 1, xx = x + k9 % 3 - 1;
      float xv = (yy >= 0 && yy < N && xx >= 0 && xx < N) ? xb[(size_t)i * N * N + yy * N + xx] : 0.f;
      const float* __restrict__ e0 = Eb + (size_t)((oA * nci + i) * 9 + k9) * 28;
      const float* __restrict__ e1 = Eb + (size_t)((oB * nci + i) * 9 + k9) * 28;
      float kv0 = e0[25], kv1 = e1[25];
      #pragma unroll
      for (int uv = 0; uv < 25; ++uv) {
        kv0 = fmaf(e0[uv], P[uv], kv0);
        kv1 = fmaf(e1[uv], P[uv], kv1);
      }
      acc0 = fmaf(kv0, xv, acc0);
      acc1 = fmaf(kv1, xv, acc1);
    }
  }
  if (act) {
    float v0 = acc0 > 0.f ? acc0 : expm1f(acc0);
    float v1 = acc1 > 0.f ? acc1 : expm1f(acc1);
    xout[(((size_t)b * NCH + oA) * N + y) * N + x] = v0;
    xout[(((size_t)b * NCH + oB) * N + y) * N + x] = v1;
  }
}

// 4 corner pixels per (scale,b,o). Grid: 4 blocks per scale (one per corner), 64 threads.
__global__ __launch_bounds__(64) void sm_corner(
    const float* __restrict__ xi0, float* __restrict__ xo0, const float* __restrict__ im0, const float* __restrict__ E0, int N0, int nci0,
    const float* __restrict__ xi1, float* __restrict__ xo1, const float* __restrict__ im1, const float* __restrict__ E1, int N1, int nci1,
    const float* __restrict__ xi2, float* __restrict__ xo2, const float* __restrict__ im2, const float* __restrict__ E2, int N2, int nci2,
    int nb0, int nb01)
{
  const float* __restrict__ xin;
  float* __restrict__ xout;
  const float* __restrict__ img;
  const float* __restrict__ E;
  int N, nci, lb;
  int bid = blockIdx.x;
  if (bid < nb0)       { xin = xi0; xout = xo0; img = im0; E = E0; N = N0; nci = nci0; lb = bid; }
  else if (bid < nb01) { xin = xi1; xout = xo1; img = im1; E = E1; N = N1; nci = nci1; lb = bid - nb0; }
  else                 { xin = xi2; xout = xo2; img = im2; E = E2; N = N2; nci = nci2; lb = bid - nb01; }

  int corner = lb;  // 0..3
  int y = (corner & 2) ? N - 1 : 0;
  int x = (corner & 1) ? N - 1 : 0;
  int cls = ((corner & 2) ? 6 : 0) + ((corner & 1) ? 2 : 0);
  int b = threadIdx.x >> 3;
  int o = threadIdx.x & 7;

  const float* __restrict__ Eb = E + (size_t)cls * 576 * 28;
  const float* imb = img + (size_t)b * N * N;
  float P[25];
  #pragma unroll
  for (int u = 0; u < 5; ++u)
    #pragma unroll
    for (int v = 0; v < 5; ++v) {
      int gy = y + u - 2, gx = x + v - 2;
      P[u * 5 + v] = (gy >= 0 && gy < N && gx >= 0 && gx < N) ? imb[gy * N + gx] : 0.f;
    }
  const float* xb = xin + (size_t)b * nci * N * N;
  float acc = 0.f;
  for (int i = 0; i < nci; ++i) {
    #pragma unroll 1
    for (int k9 = 0; k9 < 9; ++k9) {
      int yy = y + k9 / 3 - 1, xx = x + k9 % 3 - 1;
      float xv = (yy >= 0 && yy < N && xx >= 0 && xx < N) ? xb[(size_t)i * N * N + yy * N + xx] : 0.f;
      const float* e = Eb + (size_t)((o * nci + i) * 9 + k9) * 28;
      float kv = e[25];
      #pragma unroll
      for (int uv = 0; uv < 25; ++uv) kv = fmaf(e[uv], P[uv], kv);
      acc = fmaf(kv, xv, acc);
    }
  }
  float v0 = acc > 0.f ? acc : expm1f(acc);
  xout[(((size_t)b * NCH + o) * N + y) * N + x] = v0;
}

__global__ __launch_bounds__(256) void final_merge(
    const float* __restrict__ x, const float* __restrict__ x1, const float* __restrict__ x2,
    const float* __restrict__ w5, const float* __restrict__ b5,
    const float* __restrict__ w6, const float* __restrict__ b6,
    float* __restrict__ out)
{
  int tid = blockIdx.x * 256 + threadIdx.x;
  if (tid >= 8 * 128 * 128) return;
  int xx = tid % 128, y = (tid / 128) % 128, b = tid / 16384;
  float v[NCH];
  #pragma unroll
  for (int i = 0; i < NCH; ++i) {
    v[i] = x[((size_t)(b * NCH + i) * 128 + y) * 128 + xx]
         + x1[((size_t)(b * NCH + i) * 64 + (y >> 1)) * 64 + (xx >> 1)]
         + x2[((size_t)(b * NCH + i) * 32 + (y >> 2)) * 32 + (xx >> 2)];
  }
  float o6 = b6[0];
  #pragma unroll
  for (int o = 0; o < NCH; ++o) {
    float h = b5[o];
    #pragma unroll
    for (int i = 0; i < NCH; ++i) h = fmaf(w5[o * NCH + i], v[i], h);
    h = h > 0.f ? h : expm1f(h);
    o6 = fmaf(w6[o], h, o6);
  }
  out[tid] = o6;
}

extern "C" void kernel_launch(void* const* d_in, const int* in_sizes, int n_in,
                              void* d_out, int out_size, void* d_ws, size_t ws_size,
                              hipStream_t stream) {
  const float* image = (const float*)d_in[0];
  const float* x_in  = (const float*)d_in[1];
  const float* iW1   = (const float*)d_in[2];
  const float* ib1   = (const float*)d_in[3];
  const float* iW2   = (const float*)d_in[4];
  const float* ib2   = (const float*)d_in[5];
  const float* bW1   = (const float*)d_in[6];
  const float* bb1   = (const float*)d_in[7];
  const float* bW2   = (const float*)d_in[8];
  const float* bb2   = (const float*)d_in[9];
  const float* w5    = (const float*)d_in[10];
  const float* b5    = (const float*)d_in[11];
  const float* w6    = (const float*)d_in[12];
  const float* b6    = (const float*)d_in[13];
  float* ws = (float*)d_ws;

  float* F   = ws + OFF_F;
  float* Bab = ws + OFF_BAB;
  float* E   = ws + OFF_E;
  float* i1  = ws + OFF_I1;
  float* i2  = ws + OFF_I2;
  float* xA  = ws + OFF_XA;
  float* xB  = ws + OFF_XB;
  float* x1A = ws + OFF_X1A;
  float* x1B = ws + OFF_X1B;
  float* x2A = ws + OFF_X2A;
  float* x2B = ws + OFF_X2B;

  precomp_f<<<2370, 256, 0, stream>>>(iW1, iW2, ib1, bW1, bW2, bb1, F, Bab);
  precomp_e<<<6582, 256, 0, stream>>>(F, Bab, ib2, bb2, E);
  img_down<<<160, 256, 0, stream>>>(image, i1, i2);

  const size_t EBLK = (size_t)9 * 576 * 28;
  const size_t EMID = (size_t)4 * 576 * 28;  // interior class offset

  // ---- init block (blk 0, nc_in = 1, N = 128): 8b*32tiles*4og = 1024 blocks ----
  sm_apply<<<1024, 256, 0, stream>>>(
      x_in, xA, image, E + EMID, 128, 1,
      x_in, xA, image, E + EMID, 128, 1,
      x_in, xA, image, E + EMID, 128, 1,
      1024, 1024);
  sm_edge<<<64, 256, 0, stream>>>(
      x_in, xA, image, E, 128, 1,
      x_in, xA, image, E, 128, 1,
      x_in, xA, image, E, 128, 1,
      64, 64);
  sm_corner<<<4, 64, 0, stream>>>(
      x_in, xA, image, E, 128, 1,
      x_in, xA, image, E, 128, 1,
      x_in, xA, image, E, 128, 1,
      4, 4);
  x_down<<<1280, 256, 0, stream>>>(xA, x1A, x2A);

  float* xr = xA; float* xw = xB;
  float* x1r = x1A; float* x1w = x1B;
  float* x2r = x2A; float* x2w = x2B;
  for (int t = 0; t < 4; ++t) {
    int blk0 = 1 + 3 * t, blk1 = 2 + 3 * t, blk2 = 3 + 3 * t;
    const float* e0 = E + blk0 * EBLK;
    const float* e1 = E + blk1 * EBLK;
    const float* e2 = E + blk2 * EBLK;
    // blocks: s0 = 8*32*4 = 1024, s1 = 8*8*4 = 256, s2 = 8*2*4 = 64 -> 1344
    sm_apply<<<1344, 256, 0, stream>>>(
        xr, xw, image, e0 + EMID, 128, 8,
        x1r, x1w, i1, e1 + EMID, 64, 8,
        x2r, x2w, i2, e2 + EMID, 32, 8,
        1024, 1280);
    // edge blocks: s0: 4*8*2 = 64, s1: 4*8*1 = 32, s2: 4*8*1 = 32 -> 128
    sm_edge<<<128, 256, 0, stream>>>(
        xr, xw, image, e0, 128, 8,
        x1r, x1w, i1, e1, 64, 8,
        x2r, x2w, i2, e2, 32, 8,
        64, 96);
    sm_corner<<<12, 64, 0, stream>>>(
        xr, xw, image, e0, 128, 8,
        x1r, x1w, i1, e1, 64, 8,
        x2r, x2w, i2, e2, 32, 8,
        4, 8);
    float* tmp;
    tmp = xr; xr = xw; xw = tmp;
    tmp = x1r; x1r = x1w; x1w = tmp;
    tmp = x2r; x2r = x2w; x2w = tmp;
  }
  final_merge<<<512, 256, 0, stream>>>(xr, x1r, x2r, w5, b5, w6, b6, (float*)d_out);
}

// Round 3
// 557.224 us; speedup vs baseline: 1.8240x; 1.4616x over previous
//
#include <hip/hip_runtime.h>
#include <math.h>

#define NCH 8
#define HID 20

// ---- workspace layout (float offsets) ----
#define OFF_F    0u            // 13*576*81   = 606528
#define OFF_BAB  606528u       // 13*576*9    = 67392
#define OFF_E    673920u       // 13*9*576*28 = 1886976  (row: E[0..24], [25]=beta)
#define OFF_I1   2560896u      // 8*64*64
#define OFF_I2   2593664u      // 8*32*32
#define OFF_XA   2601856u      // 8*8*128*128
#define OFF_XB   3650432u
#define OFF_X1A  4699008u      // 8*8*64*64
#define OFF_X1B  4961152u
#define OFF_X2A  5223296u      // 8*8*32*32
#define OFF_X2B  5288832u

#define EBLKF ((size_t)9 * 576 * 28)
#define EMIDF ((size_t)4 * 576 * 28)

// K1: precomp_f (F/Bab) + img_down fused (independent work, block-split).
__global__ __launch_bounds__(256) void precomp_f_imgdown(
    const float* __restrict__ iW1, const float* __restrict__ iW2, const float* __restrict__ ib1,
    const float* __restrict__ bW1, const float* __restrict__ bW2, const float* __restrict__ bb1,
    float* __restrict__ F, float* __restrict__ Bab,
    const float* __restrict__ image, float* __restrict__ i1, float* __restrict__ i2)
{
  if (blockIdx.x >= 2370) {
    int tid = (blockIdx.x - 2370) * 256 + threadIdx.x;
    if (tid < 8 * 64 * 64) {
      int xx = tid % 64, y = (tid / 64) % 64, b = tid / 4096;
      const float* p = image + ((size_t)b * 128 + y * 2) * 128 + xx * 2;
      i1[tid] = 0.25f * (p[0] + p[1] + p[128] + p[129]);
    } else {
      int t = tid - 8 * 64 * 64;
      if (t >= 8 * 32 * 32) return;
      int xx = t % 32, y = (t / 32) % 32, b = t / 1024;
      const float* p = image + ((size_t)b * 128 + y * 4) * 128 + xx * 4;
      float s = 0.f;
      #pragma unroll
      for (int rr = 0; rr < 4; ++rr)
        #pragma unroll
        for (int cc = 0; cc < 4; ++cc) s += p[rr * 128 + cc];
      i2[t] = s * 0.0625f;
    }
    return;
  }
  int tid = blockIdx.x * 256 + threadIdx.x;
  if (tid >= 13 * 576 * 81) return;
  int ab9 = tid % 81;
  int rest = tid / 81;
  int p = rest % 576;
  int blk = rest / 576;
  if (blk == 0 && p >= 72) return;
  int ab = ab9 / 9, apbp = ab9 % 9;
  const float *W2, *W1, *b1;
  if (blk == 0) { W2 = iW2; W1 = iW1; b1 = ib1; }
  else {
    W2 = bW2 + (size_t)(blk - 1) * 576 * HID * 9;
    W1 = bW1 + (size_t)(blk - 1) * 64 * HID * 9;
    b1 = bb1 + (size_t)(blk - 1) * 64 * HID;
  }
  int g = p / 9;
  const float* w2p = W2 + (size_t)p * HID * 9 + ab;
  const float* w1p = W1 + (size_t)g * HID * 9 + apbp;
  float s = 0.f;
  #pragma unroll
  for (int cc = 0; cc < HID; ++cc) s = fmaf(w2p[cc * 9], w1p[cc * 9], s);
  F[(size_t)(blk * 576 + p) * 81 + ab9] = s;
  if (apbp == 0) {
    const float* b1p = b1 + g * HID;
    float sb = 0.f;
    #pragma unroll
    for (int cc = 0; cc < HID; ++cc) sb = fmaf(w2p[cc * 9], b1p[cc], sb);
    Bab[(size_t)(blk * 576 + p) * 9 + ab] = sb;
  }
}

// K2: E-class tables. cls = yclass*3+xclass; restricts valid W2 taps at borders.
__global__ __launch_bounds__(256) void precomp_e(
    const float* __restrict__ F, const float* __restrict__ Bab,
    const float* __restrict__ ib2, const float* __restrict__ bb2,
    float* __restrict__ E)
{
  int tid = blockIdx.x * 256 + threadIdx.x;
  if (tid >= 13 * 9 * 576 * 25) return;
  int uv = tid % 25;
  int rest = tid / 25;
  int p = rest % 576;
  int rest2 = rest / 576;
  int cls = rest2 % 9;
  int blk = rest2 / 9;
  if (blk == 0 && p >= 72) return;
  int yc = cls / 3, xc = cls % 3;
  int alo = (yc == 0) ? 1 : 0, ahi = (yc == 2) ? 1 : 2;
  int blo = (xc == 0) ? 1 : 0, bhi = (xc == 2) ? 1 : 2;
  int u = uv / 5, v = uv % 5;
  const float* Fp = F + (size_t)(blk * 576 + p) * 81;
  float s = 0.f;
  for (int a = alo; a <= ahi; ++a) {
    int a2 = u - a;
    if (a2 < 0 || a2 > 2) continue;
    for (int bq = blo; bq <= bhi; ++bq) {
      int b2i = v - bq;
      if (b2i < 0 || b2i > 2) continue;
      s += Fp[(a * 3 + bq) * 9 + a2 * 3 + b2i];
    }
  }
  float* Ep = E + (size_t)((blk * 9 + cls) * 576 + p) * 28;
  Ep[uv] = s;
  if (uv == 0) {
    float beta = (blk == 0) ? ib2[p] : bb2[(size_t)(blk - 1) * 576 + p];
    const float* Bp = Bab + (size_t)(blk * 576 + p) * 9;
    for (int a = alo; a <= ahi; ++a)
      for (int bq = blo; bq <= bhi; ++bq)
        beta += Bp[a * 3 + bq];
    Ep[25] = beta;
  }
}

__global__ __launch_bounds__(256) void x_down(
    const float* __restrict__ x, float* __restrict__ x1, float* __restrict__ x2)
{
  int tid = blockIdx.x * 256 + threadIdx.x;
  if (tid < 8 * NCH * 64 * 64) {
    int xx = tid % 64, y = (tid / 64) % 64, rest = tid / 4096;
    const float* p = x + ((size_t)rest * 128 + y * 2) * 128 + xx * 2;
    x1[tid] = 0.25f * (p[0] + p[1] + p[128] + p[129]);
  } else {
    int t = tid - 8 * NCH * 64 * 64;
    if (t >= 8 * NCH * 32 * 32) return;
    int xx = t % 32, y = (t / 32) % 32, rest = t / 1024;
    const float* p = x + ((size_t)rest * 128 + y * 4) * 128 + xx * 4;
    float s = 0.f;
    #pragma unroll
    for (int rr = 0; rr < 4; ++rr)
      #pragma unroll
      for (int cc = 0; cc < 4; ++cc) s += p[rr * 128 + cc];
    x2[t] = s * 0.0625f;
  }
}

#define TW 32
#define TH 16

// Unified per-step kernel: interior tiles + edge strips + corners in ONE launch.
// Interior blocks skip border-pixel stores (edge/corner blocks own those -> no race).
// E passed per scale is the 9-class table base; interior uses class 4 (EMIDF).
__global__ __launch_bounds__(256, 4) void sm_step(
    const float* __restrict__ xi0, float* __restrict__ xo0, const float* __restrict__ im0, const float* __restrict__ E0, int N0, int nci0,
    const float* __restrict__ xi1, float* __restrict__ xo1, const float* __restrict__ im1, const float* __restrict__ E1, int N1, int nci1,
    const float* __restrict__ xi2, float* __restrict__ xo2, const float* __restrict__ im2, const float* __restrict__ E2, int N2, int nci2,
    int i0, int i01, int i012, int e0e, int e01e, int e012e)
{
  __shared__ float xs[NCH][TH + 2][TW + 2];
  __shared__ float is[TH + 4][TW + 4];

  int bid = blockIdx.x;
  const float* __restrict__ xin;
  float* __restrict__ xout;
  const float* __restrict__ img;
  const float* __restrict__ E;
  int N, nci;

  if (bid < i012) {
    // ---------------- interior ----------------
    int lb, s;
    if (bid < i0)       { s = 0; lb = bid; }
    else if (bid < i01) { s = 1; lb = bid - i0; }
    else                { s = 2; lb = bid - i01; }
    if (s == 0)      { xin = xi0; xout = xo0; img = im0; E = E0; N = N0; nci = nci0; }
    else if (s == 1) { xin = xi1; xout = xo1; img = im1; E = E1; N = N1; nci = nci1; }
    else             { xin = xi2; xout = xo2; img = im2; E = E2; N = N2; nci = nci2; }

    int og = lb & 3;
    int rem = lb >> 2;
    int tilesx = N / TW;
    int tiles = tilesx * (N / TH);
    int b = rem / tiles;
    int trem = rem % tiles;
    int ty = trem / tilesx, tx = trem % tilesx;
    int X0 = tx * TW, Y0 = ty * TH;

    const float* imgb = img + (size_t)b * N * N;
    for (int idx = threadIdx.x; idx < (TH + 4) * (TW + 4); idx += 256) {
      int rr = idx / (TW + 4), cc = idx % (TW + 4);
      int gy = Y0 + rr - 2, gx = X0 + cc - 2;
      float v = 0.f;
      if (gy >= 0 && gy < N && gx >= 0 && gx < N) v = imgb[gy * N + gx];
      is[rr][cc] = v;
    }
    const float* xinb = xin + (size_t)b * nci * N * N;
    for (int idx = threadIdx.x; idx < nci * (TH + 2) * (TW + 2); idx += 256) {
      int cc = idx % (TW + 2);
      int rr = idx / (TW + 2);
      int r2 = rr % (TH + 2);
      int i = rr / (TH + 2);
      int gy = Y0 + r2 - 1, gx = X0 + cc - 1;
      float v = 0.f;
      if (gy >= 0 && gy < N && gx >= 0 && gx < N) v = xinb[(size_t)i * N * N + gy * N + gx];
      xs[i][r2][cc] = v;
    }
    __syncthreads();

    int c = threadIdx.x & 31;
    int r = threadIdx.x >> 5;   // 0..7
    int R = r * 2;              // pixel rows R, R+1 (adjacent -> patches share 4 rows)

    // 30 unique patch values: rows R..R+5, cols c..c+4 of is[][]
    float pr[6][5];
    #pragma unroll
    for (int u = 0; u < 6; ++u)
      #pragma unroll
      for (int v = 0; v < 5; ++v) pr[u][v] = is[R + u][c + v];
    // Pin in VGPRs: asm-defined values cannot be rematerialized from LDS.
    asm volatile("" : "+v"(pr[0][0]), "+v"(pr[0][1]), "+v"(pr[0][2]), "+v"(pr[0][3]), "+v"(pr[0][4]),
                     "+v"(pr[1][0]), "+v"(pr[1][1]), "+v"(pr[1][2]), "+v"(pr[1][3]), "+v"(pr[1][4]),
                     "+v"(pr[2][0]), "+v"(pr[2][1]), "+v"(pr[2][2]), "+v"(pr[2][3]), "+v"(pr[2][4]));
    asm volatile("" : "+v"(pr[3][0]), "+v"(pr[3][1]), "+v"(pr[3][2]), "+v"(pr[3][3]), "+v"(pr[3][4]),
                     "+v"(pr[4][0]), "+v"(pr[4][1]), "+v"(pr[4][2]), "+v"(pr[4][3]), "+v"(pr[4][4]),
                     "+v"(pr[5][0]), "+v"(pr[5][1]), "+v"(pr[5][2]), "+v"(pr[5][3]), "+v"(pr[5][4]));

    float a00 = 0.f, a01 = 0.f, a10 = 0.f, a11 = 0.f;  // [o][px]
    const int o0 = og * 2;
    const float* __restrict__ Ea = E + EMIDF + (size_t)(o0 * nci) * 9 * 28;
    const float* __restrict__ Eb = Ea + (size_t)nci * 9 * 28;

    #pragma unroll 1
    for (int i = 0; i < nci; ++i) {
      #pragma unroll
      for (int k9 = 0; k9 < 9; ++k9) {
        const int dy = k9 / 3, dx = k9 % 3;
        const float xp0 = xs[i][R + dy][c + dx];
        const float xp1 = xs[i][R + 1 + dy][c + dx];
        const float* __restrict__ e0 = Ea + (size_t)(i * 9 + k9) * 28;
        const float* __restrict__ e1 = Eb + (size_t)(i * 9 + k9) * 28;
        float k00 = e0[25], k01 = e0[25], k10 = e1[25], k11 = e1[25];
        #pragma unroll
        for (int u = 0; u < 5; ++u)
          #pragma unroll
          for (int v = 0; v < 5; ++v) {
            const int uv = u * 5 + v;
            k00 = fmaf(e0[uv], pr[u][v], k00);
            k01 = fmaf(e0[uv], pr[u + 1][v], k01);
            k10 = fmaf(e1[uv], pr[u][v], k10);
            k11 = fmaf(e1[uv], pr[u + 1][v], k11);
          }
        a00 = fmaf(k00, xp0, a00);
        a01 = fmaf(k01, xp1, a01);
        a10 = fmaf(k10, xp0, a10);
        a11 = fmaf(k11, xp1, a11);
      }
    }

    const int gx = X0 + c, gy0 = Y0 + R, gy1 = Y0 + R + 1;
    float* yb = xout + (size_t)b * NCH * N * N;
    bool cok = (gx > 0) & (gx < N - 1);
    if (cok & (gy0 > 0) & (gy0 < N - 1)) {
      float v00 = a00 > 0.f ? a00 : expm1f(a00);
      float v10 = a10 > 0.f ? a10 : expm1f(a10);
      yb[(size_t)o0 * N * N + gy0 * N + gx] = v00;
      yb[(size_t)(o0 + 1) * N * N + gy0 * N + gx] = v10;
    }
    if (cok & (gy1 > 0) & (gy1 < N - 1)) {
      float v01 = a01 > 0.f ? a01 : expm1f(a01);
      float v11 = a11 > 0.f ? a11 : expm1f(a11);
      yb[(size_t)o0 * N * N + gy1 * N + gx] = v01;
      yb[(size_t)(o0 + 1) * N * N + gy1 * N + gx] = v11;
    }
    return;
  }

  if (bid < e012e) {
    // ---------------- edges (excl corners) ----------------
    int eb = bid - i012;
    int lb, s;
    if (eb < e0e - i012)        { s = 0; lb = eb; }
    else if (eb < e01e - i012)  { s = 1; lb = eb - (e0e - i012); }
    else                        { s = 2; lb = eb - (e01e - i012); }
    if (s == 0)      { xin = xi0; xout = xo0; img = im0; E = E0; N = N0; nci = nci0; }
    else if (s == 1) { xin = xi1; xout = xo1; img = im1; E = E1; N = N1; nci = nci1; }
    else             { xin = xi2; xout = xo2; img = im2; E = E2; N = N2; nci = nci2; }

    int H = (N - 2 + 63) / 64;
    int half = lb % H;
    int b = (lb / H) % 8;
    int side = lb / (H * 8);

    int lane = threadIdx.x & 63;
    int orow = threadIdx.x >> 6;   // 0..3 (wave-uniform)
    int pos = 1 + half * 64 + lane;
    bool act = pos < N - 1;
    if (!act) pos = 1;

    int y, x, cls;
    if (side == 0)      { y = 0;     x = pos;  cls = 1; }
    else if (side == 1) { y = N - 1; x = pos;  cls = 7; }
    else if (side == 2) { x = 0;     y = pos;  cls = 3; }
    else                { x = N - 1; y = pos;  cls = 5; }

    const float* __restrict__ Ec = E + (size_t)cls * 576 * 28;
    const float* imb = img + (size_t)b * N * N;
    float P[25];
    #pragma unroll
    for (int u = 0; u < 5; ++u)
      #pragma unroll
      for (int v = 0; v < 5; ++v) {
        int gy = y + u - 2, gx = x + v - 2;
        P[u * 5 + v] = (gy >= 0 && gy < N && gx >= 0 && gx < N) ? imb[gy * N + gx] : 0.f;
      }

    const float* xb = xin + (size_t)b * nci * N * N;
    float acc0 = 0.f, acc1 = 0.f;
    const int oA = orow, oB = orow + 4;
    for (int i = 0; i < nci; ++i) {
      #pragma unroll 1
      for (int k9 = 0; k9 < 9; ++k9) {
        int yy = y + k9 / 3 - 1, xx = x + k9 % 3 - 1;
        float xv = (yy >= 0 && yy < N && xx >= 0 && xx < N) ? xb[(size_t)i * N * N + yy * N + xx] : 0.f;
        const float* __restrict__ e0 = Ec + (size_t)((oA * nci + i) * 9 + k9) * 28;
        const float* __restrict__ e1 = Ec + (size_t)((oB * nci + i) * 9 + k9) * 28;
        float kv0 = e0[25], kv1 = e1[25];
        #pragma unroll
        for (int uv = 0; uv < 25; ++uv) {
          kv0 = fmaf(e0[uv], P[uv], kv0);
          kv1 = fmaf(e1[uv], P[uv], kv1);
        }
        acc0 = fmaf(kv0, xv, acc0);
        acc1 = fmaf(kv1, xv, acc1);
      }
    }
    if (act) {
      float v0 = acc0 > 0.f ? acc0 : expm1f(acc0);
      float v1 = acc1 > 0.f ? acc1 : expm1f(acc1);
      xout[(((size_t)b * NCH + oA) * N + y) * N + x] = v0;
      xout[(((size_t)b * NCH + oB) * N + y) * N + x] = v1;
    }
    return;
  }

  // ---------------- corners: one block per scale, wave = one corner ----------------
  {
    int s = bid - e012e;
    if (s == 0)      { xin = xi0; xout = xo0; img = im0; E = E0; N = N0; nci = nci0; }
    else if (s == 1) { xin = xi1; xout = xo1; img = im1; E = E1; N = N1; nci = nci1; }
    else             { xin = xi2; xout = xo2; img = im2; E = E2; N = N2; nci = nci2; }

    int corner = threadIdx.x >> 6;  // 0..3
    int lane = threadIdx.x & 63;
    int y = (corner & 2) ? N - 1 : 0;
    int x = (corner & 1) ? N - 1 : 0;
    int cls = ((corner & 2) ? 6 : 0) + ((corner & 1) ? 2 : 0);
    int b = lane >> 3;
    int o = lane & 7;

    const float* __restrict__ Ec = E + (size_t)cls * 576 * 28;
    const float* imb = img + (size_t)b * N * N;
    float P[25];
    #pragma unroll
    for (int u = 0; u < 5; ++u)
      #pragma unroll
      for (int v = 0; v < 5; ++v) {
        int gy = y + u - 2, gx = x + v - 2;
        P[u * 5 + v] = (gy >= 0 && gy < N && gx >= 0 && gx < N) ? imb[gy * N + gx] : 0.f;
      }
    const float* xb = xin + (size_t)b * nci * N * N;
    float acc = 0.f;
    for (int i = 0; i < nci; ++i) {
      #pragma unroll 1
      for (int k9 = 0; k9 < 9; ++k9) {
        int yy = y + k9 / 3 - 1, xx = x + k9 % 3 - 1;
        float xv = (yy >= 0 && yy < N && xx >= 0 && xx < N) ? xb[(size_t)i * N * N + yy * N + xx] : 0.f;
        const float* e = Ec + (size_t)((o * nci + i) * 9 + k9) * 28;
        float kv = e[25];
        #pragma unroll
        for (int uv = 0; uv < 25; ++uv) kv = fmaf(e[uv], P[uv], kv);
        acc = fmaf(kv, xv, acc);
      }
    }
    float v0 = acc > 0.f ? acc : expm1f(acc);
    xout[(((size_t)b * NCH + o) * N + y) * N + x] = v0;
  }
}

__global__ __launch_bounds__(256) void final_merge(
    const float* __restrict__ x, const float* __restrict__ x1, const float* __restrict__ x2,
    const float* __restrict__ w5, const float* __restrict__ b5,
    const float* __restrict__ w6, const float* __restrict__ b6,
    float* __restrict__ out)
{
  int tid = blockIdx.x * 256 + threadIdx.x;
  if (tid >= 8 * 128 * 128) return;
  int xx = tid % 128, y = (tid / 128) % 128, b = tid / 16384;
  float v[NCH];
  #pragma unroll
  for (int i = 0; i < NCH; ++i) {
    v[i] = x[((size_t)(b * NCH + i) * 128 + y) * 128 + xx]
         + x1[((size_t)(b * NCH + i) * 64 + (y >> 1)) * 64 + (xx >> 1)]
         + x2[((size_t)(b * NCH + i) * 32 + (y >> 2)) * 32 + (xx >> 2)];
  }
  float o6 = b6[0];
  #pragma unroll
  for (int o = 0; o < NCH; ++o) {
    float h = b5[o];
    #pragma unroll
    for (int i = 0; i < NCH; ++i) h = fmaf(w5[o * NCH + i], v[i], h);
    h = h > 0.f ? h : expm1f(h);
    o6 = fmaf(w6[o], h, o6);
  }
  out[tid] = o6;
}

extern "C" void kernel_launch(void* const* d_in, const int* in_sizes, int n_in,
                              void* d_out, int out_size, void* d_ws, size_t ws_size,
                              hipStream_t stream) {
  const float* image = (const float*)d_in[0];
  const float* x_in  = (const float*)d_in[1];
  const float* iW1   = (const float*)d_in[2];
  const float* ib1   = (const float*)d_in[3];
  const float* iW2   = (const float*)d_in[4];
  const float* ib2   = (const float*)d_in[5];
  const float* bW1   = (const float*)d_in[6];
  const float* bb1   = (const float*)d_in[7];
  const float* bW2   = (const float*)d_in[8];
  const float* bb2   = (const float*)d_in[9];
  const float* w5    = (const float*)d_in[10];
  const float* b5    = (const float*)d_in[11];
  const float* w6    = (const float*)d_in[12];
  const float* b6    = (const float*)d_in[13];
  float* ws = (float*)d_ws;

  float* F   = ws + OFF_F;
  float* Bab = ws + OFF_BAB;
  float* E   = ws + OFF_E;
  float* i1  = ws + OFF_I1;
  float* i2  = ws + OFF_I2;
  float* xA  = ws + OFF_XA;
  float* xB  = ws + OFF_XB;
  float* x1A = ws + OFF_X1A;
  float* x1B = ws + OFF_X1B;
  float* x2A = ws + OFF_X2A;
  float* x2B = ws + OFF_X2B;

  precomp_f_imgdown<<<2530, 256, 0, stream>>>(iW1, iW2, ib1, bW1, bW2, bb1, F, Bab, image, i1, i2);
  precomp_e<<<6582, 256, 0, stream>>>(F, Bab, ib2, bb2, E);

  // ---- init (blk 0, nc_in=1, scale0 only): interior 1024, edge 64, corner 1 ----
  sm_step<<<1089, 256, 0, stream>>>(
      x_in, xA, image, E, 128, 1,
      x_in, xA, image, E, 128, 1,
      x_in, xA, image, E, 128, 1,
      1024, 1024, 1024, 1088, 1088, 1088);
  x_down<<<1280, 256, 0, stream>>>(xA, x1A, x2A);

  float* xr = xA; float* xw = xB;
  float* x1r = x1A; float* x1w = x1B;
  float* x2r = x2A; float* x2w = x2B;
  for (int t = 0; t < 4; ++t) {
    const float* e0 = E + (1 + 3 * t) * EBLKF;
    const float* e1 = E + (2 + 3 * t) * EBLKF;
    const float* e2 = E + (3 + 3 * t) * EBLKF;
    // interior: 1024 + 256 + 64 = 1344; edges: 64 + 32 + 32 = 128; corners: 3
    sm_step<<<1475, 256, 0, stream>>>(
        xr, xw, image, e0, 128, 8,
        x1r, x1w, i1, e1, 64, 8,
        x2r, x2w, i2, e2, 32, 8,
        1024, 1280, 1344, 1408, 1440, 1472);
    float* tmp;
    tmp = xr; xr = xw; xw = tmp;
    tmp = x1r; x1r = x1w; x1w = tmp;
    tmp = x2r; x2r = x2w; x2w = tmp;
  }
  final_merge<<<512, 256, 0, stream>>>(xr, x1r, x2r, w5, b5, w6, b6, (float*)d_out);
}